// Round 4
// baseline (182.285 us; speedup 1.0000x reference)
//
#include <hip/hip_runtime.h>
#include <hip/hip_bf16.h>

#define BATCH 2
#define SLEN 2048
#define NH 12
#define DM 768
#define DH 64
#define ROWS (BATCH*SLEN)   // 4096
#define NQKV (3*DM)         // 2304
#define NCHUNK 40           // split-K chunks per bh (q-tile=128, chunk = up to 8 k-tiles)

typedef __attribute__((ext_vector_type(8))) short bf16x8;
typedef __attribute__((ext_vector_type(4))) float f32x4;
typedef __attribute__((ext_vector_type(16))) float f32x16;
typedef unsigned short u16;
typedef unsigned int u32;
typedef __attribute__((ext_vector_type(4))) unsigned short u16x4;
typedef __attribute__((ext_vector_type(8))) unsigned short u16x8;

__device__ __forceinline__ u16 f2b(float f) {
    unsigned int u = __builtin_bit_cast(unsigned int, f);
    unsigned int r = (u + 0x7FFFu + ((u >> 16) & 1u)) >> 16;
    return (u16)r;
}
__device__ __forceinline__ float b2f(u16 v) {
    unsigned int u = ((unsigned int)v) << 16;
    return __builtin_bit_cast(float, u);
}

// async global->LDS, 16B per lane. LDS dest = wave-uniform base + lane*16.
__device__ __forceinline__ void gload16(const u16* g, u16* l) {
    __builtin_amdgcn_global_load_lds(
        (const __attribute__((address_space(1))) unsigned int*)g,
        (__attribute__((address_space(3))) unsigned int*)l,
        16, 0, 0);
}

// ---------------- merged pack kernel (x -> bf16, W_QKV -> Bt layout, W_O -> Bt layout) ----
// grid 2112 = 1536 (x) + 432 (wqkv) + 144 (wo); branch is block-uniform.

__global__ __launch_bounds__(256) void pack_all(const float* __restrict__ x,
                                                const float* __restrict__ WQ, const float* __restrict__ WK,
                                                const float* __restrict__ WV, const float* __restrict__ WO,
                                                u16* __restrict__ xb, u16* __restrict__ wqkv,
                                                u16* __restrict__ wo) {
    __shared__ u16 L[64 * 72];
    int blk = blockIdx.x;
    int t = threadIdx.x;
    if (blk < 1536) {
        int i = blk * 256 + t;
        const float4* xv = (const float4*)x;
        float4 a = xv[i * 2], b = xv[i * 2 + 1];
        u16x8 o;
        o[0] = f2b(a.x); o[1] = f2b(a.y); o[2] = f2b(a.z); o[3] = f2b(a.w);
        o[4] = f2b(b.x); o[5] = f2b(b.y); o[6] = f2b(b.z); o[7] = f2b(b.w);
        *(u16x8*)(xb + (size_t)i * 8) = o;
    } else if (blk < 1968) {
        int idx = blk - 1536;
        int mt = idx % 12, h = (idx / 12) % 12, sel = idx / 144;
        const float* W = sel == 0 ? WQ : (sel == 1 ? WK : WV);
        const float* src = W + ((size_t)h * DM + mt * 64) * DH;
        for (int j = 0; j < 4; j++) {
            int i = t + 256 * j;
            int r = i >> 4, cf = i & 15;
            float4 v = ((const float4*)src)[i];
            u16x4 o; o[0] = f2b(v.x); o[1] = f2b(v.y); o[2] = f2b(v.z); o[3] = f2b(v.w);
            *(u16x4*)&L[r * 72 + cf * 4] = o;
        }
        __syncthreads();
        u16* orow = wqkv + ((size_t)(sel * DM + h * DH)) * DM + mt * 64;
        for (int j = 0; j < 16; j++) {
            int e = t + 256 * j;
            int d = e >> 6, mm = e & 63;
            orow[(size_t)d * DM + mm] = L[mm * 72 + d];
        }
    } else {
        int idx = blk - 1968;
        int bi = idx % 12, bj = idx / 12;
        for (int j = 0; j < 4; j++) {
            int i = t + 256 * j;
            int r = i >> 4, cf = i & 15;
            float4 v = ((const float4*)(WO + (size_t)(bi * 64 + r) * DM + bj * 64))[cf];
            u16x4 o; o[0] = f2b(v.x); o[1] = f2b(v.y); o[2] = f2b(v.z); o[3] = f2b(v.w);
            *(u16x4*)&L[r * 72 + cf * 4] = o;
        }
        __syncthreads();
        for (int j = 0; j < 16; j++) {
            int e = t + 256 * j;
            int c = e >> 6, r = e & 63;
            wo[(size_t)(bj * 64 + c) * DM + bi * 64 + r] = L[r * 72 + c];
        }
    }
}

// ---------------- QKV GEMM (128x96 tile, gload16 staging, XOR-swizzled LDS) ----
// grid 24x32 = 768 blocks -> one full residency wave at 3 blocks/CU, no remainder.
// V epilogue transposes via LDS so V^T [d][s] writes are 256B-contiguous rows.

__global__ __launch_bounds__(256) void gemm_qkv(const u16* __restrict__ A, const u16* __restrict__ Bt,
                                                const float* __restrict__ bQ, const float* __restrict__ bK,
                                                const float* __restrict__ bV,
                                                u16* __restrict__ Qb, u16* __restrict__ Kb, u16* __restrict__ Vb) {
    __shared__ u16 S[128 * 64 + 96 * 64];   // Al | Bl; reused as [96][136] transpose pad
    u16* Al = S;
    u16* Bl = S + 128 * 64;
    int t = threadIdx.x;
    int n0 = blockIdx.x * 96, m0 = blockIdx.y * 128;
    int lane = t & 63, w = t >> 6;
    int ln = lane & 15, qd = lane >> 4;
    int wr = (w & 1) * 64, wc = (w >> 1) * 48;
    int srow = lane >> 3, slot = lane & 7;
    f32x4 acc[4][3] = {};

    for (int kt = 0; kt < DM / 64; kt++) {
        __syncthreads();
        for (int j = 0; j < 4; j++) {
            int r = w * 32 + j * 8 + srow;
            int gc = slot ^ (r & 7);
            gload16(A + (size_t)(m0 + r) * DM + kt * 64 + gc * 8, &Al[(w * 32 + j * 8) * 64]);
        }
        for (int j = 0; j < 3; j++) {
            int r = w * 24 + j * 8 + srow;
            int gc = slot ^ (r & 7);
            gload16(Bt + (size_t)(n0 + r) * DM + kt * 64 + gc * 8, &Bl[(w * 24 + j * 8) * 64]);
        }
        __syncthreads();   // drains vmcnt -> tile visible
        for (int ks = 0; ks < 2; ks++) {
            int sl = ((ks * 4 + qd) ^ (ln & 7)) * 8;
            bf16x8 af[4], bfr[3];
            for (int rt = 0; rt < 4; rt++)
                af[rt] = *(const bf16x8*)&Al[(wr + rt * 16 + ln) * 64 + sl];
            for (int ct = 0; ct < 3; ct++)
                bfr[ct] = *(const bf16x8*)&Bl[(wc + ct * 16 + ln) * 64 + sl];
            for (int rt = 0; rt < 4; rt++)
                for (int ct = 0; ct < 3; ct++)
                    acc[rt][ct] = __builtin_amdgcn_mfma_f32_16x16x32_bf16(af[rt], bfr[ct], acc[rt][ct], 0, 0, 0);
        }
    }
    int sel = n0 / DM;                   // 768/96 = 8 tiles per sel -> uniform per block
    if (sel == 2) {
        // transpose 128(s) x 96(d) tile through LDS -> contiguous V^T row writes
        __syncthreads();                 // all LDS reads done before overwrite
        for (int ct = 0; ct < 3; ct++) {
            int c = wc + ct * 16 + ln;
            float bv = bV[n0 - 2 * DM + c];
            for (int rt = 0; rt < 4; rt++) {
                int s = wr + rt * 16 + qd * 4;
                for (int r = 0; r < 4; r++)
                    S[c * 136 + s + r] = f2b(acc[rt][ct][r] + bv);
            }
        }
        __syncthreads();
        int bb = m0 >> 11, ss0 = m0 & 2047;
        for (int it = 0; it < 6; it++) {
            int e = t + it * 256;
            int c = e >> 4, ck = e & 15;
            int gcol = n0 - 2 * DM + c;
            int hh = gcol >> 6, dd = gcol & 63;
            u16x8 v = *(const u16x8*)&S[c * 136 + ck * 8];
            *(u16x8*)&Vb[(((size_t)bb * NH + hh) * DH + dd) * SLEN + ss0 + ck * 8] = v;
        }
    } else {
        const float* bias = sel == 0 ? bQ : bK;
        u16* Out = sel == 0 ? Qb : Kb;
        const float qs = sel == 0 ? 0.125f * 1.44269504f : 1.0f;
        for (int ct = 0; ct < 3; ct++) {
            int col = n0 - sel * DM + wc + ct * 16 + ln;
            int hh = col >> 6, dd = col & 63;
            float bv = bias[col];
            for (int rt = 0; rt < 4; rt++) {
                int row = m0 + wr + rt * 16 + qd * 4;
                for (int r = 0; r < 4; r++) {
                    int rg = row + r;
                    int bb = rg >> 11, ss = rg & 2047;
                    Out[(((size_t)bb * NH + hh) * SLEN + ss) * DH + dd] = f2b((acc[rt][ct][r] + bv) * qs);
                }
            }
        }
    }
}

// ---------------- split-K flash attention, 32x32 MFMA, LDS-routed P ----
// q-tile = 128 rows, 4 waves x 32q. K/V double-buffered (gload16, XOR-swizzled),
// ONE barrier per k-tile (its vmcnt drain completes the prefetch issued at loop top).
// P scratch halved to per-kb [32q][32k] (8KB) -> LDS 40KB -> 4 blocks/CU.
// l is a VALU sum of the SAME truncated-bf16 P values fed to PV.
// grid 960 = 40 chunks x 24 bh; cid = 39 - blk/24 (LPT);
// bh = (blk%24&7)*3 + (blk%24>>3) keeps 3 bh per XCD (K/V L2 residency).

__device__ __forceinline__ void cid2qc(int cid, int& qt, int& c, int& nc) {
    if (cid < 4)       { qt = cid;                   c = 0;               nc = 1; }
    else if (cid < 12) { qt = 4 + ((cid - 4) >> 1);  c = (cid - 4) & 1;   nc = 2; }
    else if (cid < 24) { qt = 8 + (cid - 12) / 3;    c = (cid - 12) % 3;  nc = 3; }
    else               { qt = 12 + ((cid - 24) >> 2); c = (cid - 24) & 3; nc = 4; }
}

__global__ __launch_bounds__(256, 4) void attn(const u16* __restrict__ Qb, const u16* __restrict__ Kb,
                                               const u16* __restrict__ Vtg,
                                               u16* __restrict__ Po, float* __restrict__ Plv) {
    __shared__ u16 Kl[2][64 * 64];
    __shared__ u16 Vt[2][64 * 64];       // [d][k]
    __shared__ u16 Pq[4][32 * 32];       // wave-private per-kb P: [q32][k32], XOR-swizzled
    int blk = blockIdx.x;
    int cid = (NCHUNK - 1) - blk / 24;
    int j24 = blk % 24;
    int bh = (j24 & 7) * 3 + (j24 >> 3);
    int qt, c, nc;
    cid2qc(cid, qt, c, nc);
    int ntiles = 2 * qt + 2;
    int kt0 = c * ntiles / nc, kt1 = (c + 1) * ntiles / nc;
    const u16* Qp = Qb + (size_t)bh * SLEN * DH;
    const u16* Kp = Kb + (size_t)bh * SLEN * DH;
    const u16* Vp = Vtg + (size_t)bh * SLEN * DH;  // [d][s]
    int t = threadIdx.x, lane = t & 63, w = t >> 6;
    int l31 = lane & 31, h = lane >> 5;
    int qg = qt * 128 + w * 32 + l31;
    int srow = lane >> 3, slot = lane & 7;
    int sw = (l31 & 3) << 3;             // P swizzle (u16 units, bits 3-4)

    // Q fragments (B-operand): col q = lane&31, contraction d = ks*16 + 8h + e
    bf16x8 qf[4];
    for (int ks = 0; ks < 4; ks++)
        qf[ks] = *(const bf16x8*)(Qp + (size_t)qg * DH + ks * 16 + h * 8);

    f32x16 o[2] = {};    // o[d][q]: col q=lane&31, d = db*32 + (reg&3)+8*(reg>>2)+4h
    float lsum = 0.f;
    u16* Pw = Pq[w];

    auto stage = [&](int kt, int buf) {
        int k0 = kt * 64;
        for (int j = 0; j < 2; j++) {
            int r = w * 16 + j * 8 + srow;
            int gc = slot ^ (r & 7);
            gload16(Kp + (size_t)(k0 + r) * DH + gc * 8, &Kl[buf][(w * 16 + j * 8) * 64]);
            gload16(Vp + (size_t)r * SLEN + k0 + gc * 8, &Vt[buf][(w * 16 + j * 8) * 64]);
        }
    };

    stage(kt0, 0);
    __syncthreads();   // drains vmcnt -> first tile visible
    int cur = 0;
    for (int kt = kt0; kt < kt1; kt++) {
        int k0 = kt * 64;
        if (kt + 1 < kt1) stage(kt + 1, cur ^ 1);   // prefetch overlaps compute
        const u16* Kc = Kl[cur];
        const u16* Vc = Vt[cur];

        for (int kb = 0; kb < 2; kb++) {
            // QK^T: S[32k x 32q] = K_rows x Q
            f32x16 sf = {};
            for (int ks = 0; ks < 4; ks++) {
                int row = kb * 32 + l31;
                bf16x8 kf = *(const bf16x8*)&Kc[row * 64 + (((ks * 2 + h) ^ (row & 7)) * 8)];
                sf = __builtin_amdgcn_mfma_f32_32x32x16_bf16(kf, qf[ks], sf, 0, 0, 0);
            }
            if (k0 + 63 > qt * 128 + w * 32) {          // diagonal region, wave-uniform
                for (int r = 0; r < 16; r++) {
                    int kg = k0 + kb * 32 + (r & 3) + 8 * (r >> 2) + 4 * h;
                    if (kg > qg) sf[r] = -1e30f;
                }
            }
            // exp2 + truncate-to-bf16 pack via v_perm (consecutive-k pairs)
            u32 pr[8];
            for (int p = 0; p < 8; p++) {
                u32 e0 = __builtin_bit_cast(u32, exp2f(sf[2 * p]));
                u32 e1 = __builtin_bit_cast(u32, exp2f(sf[2 * p + 1]));
                pr[p] = __builtin_amdgcn_perm(e1, e0, 0x07060302u);
            }
            // l partial: sum the SAME truncated bf16 values fed to PV
            for (int p = 0; p < 8; p++) {
                lsum += __builtin_bit_cast(float, pr[p] << 16);
                lsum += __builtin_bit_cast(float, pr[p] & 0xFFFF0000u);
            }
            // store P[q=l31][k-local] pairs (regs (2p,2p+1) -> k = {0,8,16,24}+4h), swizzled
            {
                uint2 s;
                s.x = pr[0]; s.y = pr[1];
                *(uint2*)&Pw[l31 * 32 + ((4 * h) ^ sw)] = s;
                s.x = pr[2]; s.y = pr[3];
                *(uint2*)&Pw[l31 * 32 + ((8 + 4 * h) ^ sw)] = s;
                s.x = pr[4]; s.y = pr[5];
                *(uint2*)&Pw[l31 * 32 + ((16 + 4 * h) ^ sw)] = s;
                s.x = pr[6]; s.y = pr[7];
                *(uint2*)&Pw[l31 * 32 + ((24 + 4 * h) ^ sw)] = s;
            }
            // PV: read B-fragments (col q=l31, k = cc*16 + 8h + e) from swizzled LDS
            for (int cc = 0; cc < 2; cc++) {
                bf16x8 pf = *(const bf16x8*)&Pw[l31 * 32 + ((cc * 16 + 8 * h) ^ sw)];
                int ch4 = kb * 2 + cc;
                for (int db = 0; db < 2; db++) {
                    int row = db * 32 + l31;
                    bf16x8 vf = *(const bf16x8*)&Vc[row * 64 + (((ch4 * 2 + h) ^ (row & 7)) * 8)];
                    o[db] = __builtin_amdgcn_mfma_f32_32x32x16_bf16(vf, pf, o[db], 0, 0, 0);
                }
            }
        }
        __syncthreads();   // drains prefetch vmcnt; buffers safe to swap
        cur ^= 1;
    }

    size_t pid = (size_t)bh * NCHUNK + cid;
    u16* op = Po + pid * (128 * 64);      // [q-local][d]
    for (int db = 0; db < 2; db++)
        for (int rq = 0; rq < 4; rq++) {
            u16x4 ov;
            for (int j = 0; j < 4; j++) ov[j] = f2b(o[db][rq * 4 + j]);
            *(u16x4*)&op[(w * 32 + l31) * 64 + db * 32 + rq * 8 + 4 * h] = ov;
        }
    lsum += __shfl_xor(lsum, 32, 64);     // merge h-halves -> full k-sum for q=l31
    if (h == 0)
        Plv[pid * 128 + w * 32 + l31] = lsum;
}

// ---------------- output projection fused with combine ----------------
// Reads Po/Plv directly: A-tile = bf16( (Sum_cc Po)/l ) built during staging
// (reg-stage + swizzled ds_write). Linv[12][64] precomputed once per block.
// 1D grid 512, XCD-grouped decode: the 8 n-blocks of one m-row-block share an
// XCD so Po partials are read from HBM once and L2-served 8x.

__global__ __launch_bounds__(256) void gemm_proj(const u16* __restrict__ Po, const float* __restrict__ Plv,
                                                 const u16* __restrict__ Bt, const float* __restrict__ bO,
                                                 float* __restrict__ out) {
    __shared__ u16 Al[64 * 64];
    __shared__ u16 Bl[96 * 64];
    __shared__ float Linv[12][64];
    int blk = blockIdx.x;
    int xcd = blk & 7, idx = blk >> 3;          // idx in [0,64)
    int by = xcd * 8 + (idx >> 3), bx = idx & 7;
    int n0 = bx * 96, m0 = by * 64;
    int b = m0 >> 11, qtile = (m0 >> 7) & 15, qh = m0 & 127;
    int nc = qtile < 4 ? 1 : (qtile < 8 ? 2 : (qtile < 12 ? 3 : 4));
    int base = qtile < 4 ? qtile
             : (qtile < 8 ? 4 + (qtile - 4) * 2
             : (qtile < 12 ? 12 + (qtile - 8) * 3
                           : 24 + (qtile - 12) * 4));
    int t = threadIdx.x;
    int lane = t & 63, w = t >> 6;
    int ln = lane & 15, qd = lane >> 4;
    int wr = (w & 1) * 32, wc = (w >> 1) * 48;
    int srow = lane >> 3, slot = lane & 7;
    f32x4 acc[2][3] = {};

    for (int j = 0; j < 3; j++) {
        int e = t + 256 * j;                    // 768 = 12 heads x 64 rows
        int hh = e >> 6, q = e & 63;
        size_t pidb = ((size_t)(b * NH + hh)) * NCHUNK + base;
        float ls = 0.f;
        for (int cc = 0; cc < nc; cc++) ls += Plv[(pidb + cc) * 128 + qh + q];
        Linv[hh][q] = 1.0f / ls;
    }

    for (int kt = 0; kt < DM / 64; kt++) {      // k-tile == head
        __syncthreads();                        // covers Linv on kt=0; LDS reuse after
        size_t pidb = ((size_t)(b * NH + kt)) * NCHUNK + base;
        for (int j = 0; j < 2; j++) {
            int r = (t >> 3) + 32 * j;
            int c8 = (t & 7) * 8;
            float a[8] = {};
            for (int cc = 0; cc < nc; cc++) {
                u16x8 v = *(const u16x8*)(Po + (pidb + cc) * (128 * 64) + (size_t)(qh + r) * 64 + c8);
                for (int e = 0; e < 8; e++) a[e] += b2f(v[e]);
            }
            float il = Linv[kt][r];
            u16x8 ov;
            for (int e = 0; e < 8; e++) ov[e] = f2b(a[e] * il);
            *(u16x8*)&Al[r * 64 + (((t & 7) ^ (r & 7)) * 8)] = ov;
        }
        for (int j = 0; j < 3; j++) {
            int r = w * 24 + j * 8 + srow;
            int gc = slot ^ (r & 7);
            gload16(Bt + (size_t)(n0 + r) * DM + kt * 64 + gc * 8, &Bl[(w * 24 + j * 8) * 64]);
        }
        __syncthreads();                        // drains vmcnt + lgkm -> tile visible
        for (int ks = 0; ks < 2; ks++) {
            int sl = ((ks * 4 + qd) ^ (ln & 7)) * 8;
            bf16x8 af[2], bfr[3];
            for (int rt = 0; rt < 2; rt++)
                af[rt] = *(const bf16x8*)&Al[(wr + rt * 16 + ln) * 64 + sl];
            for (int ct = 0; ct < 3; ct++)
                bfr[ct] = *(const bf16x8*)&Bl[(wc + ct * 16 + ln) * 64 + sl];
            for (int rt = 0; rt < 2; rt++)
                for (int ct = 0; ct < 3; ct++)
                    acc[rt][ct] = __builtin_amdgcn_mfma_f32_16x16x32_bf16(af[rt], bfr[ct], acc[rt][ct], 0, 0, 0);
        }
    }
    for (int ct = 0; ct < 3; ct++) {
        int col = n0 + wc + ct * 16 + ln;
        float bv = bO[col];
        for (int rt = 0; rt < 2; rt++) {
            int row = m0 + wr + rt * 16 + qd * 4;
            for (int r = 0; r < 4; r++)
                out[(size_t)(row + r) * DM + col] = acc[rt][ct][r] + bv;
        }
    }
}

// ---------------- launch ----------------

extern "C" void kernel_launch(void* const* d_in, const int* in_sizes, int n_in,
                              void* d_out, int out_size, void* d_ws, size_t ws_size,
                              hipStream_t stream) {
    const float* x  = (const float*)d_in[0];
    const float* WQ = (const float*)d_in[1];
    const float* bQ = (const float*)d_in[2];
    const float* WK = (const float*)d_in[3];
    const float* bK = (const float*)d_in[4];
    const float* WV = (const float*)d_in[5];
    const float* bV = (const float*)d_in[6];
    const float* WO = (const float*)d_in[7];
    const float* bO = (const float*)d_in[8];
    float* out = (float*)d_out;

    u16* xb   = (u16*)d_ws;                        // [4096][768]
    u16* wqkv = xb + (size_t)ROWS * DM;            // [2304][768]
    u16* wo   = wqkv + (size_t)NQKV * DM;          // [768][768]
    u16* Qb   = wo + (size_t)DM * DM;
    size_t hsz = (size_t)BATCH * NH * SLEN * DH;
    u16* Kb   = Qb + hsz;
    u16* Vb   = Kb + hsz;                          // V^T [b,h,d,s]
    u16* Po   = Vb + hsz;                          // partials o: [24*40][128][64] bf16
    float* Pl = (float*)(Po + (size_t)BATCH * NH * NCHUNK * 128 * 64);

    pack_all<<<2112, 256, 0, stream>>>(x, WQ, WK, WV, WO, xb, wqkv, wo);
    gemm_qkv<<<dim3(NQKV / 96, ROWS / 128), 256, 0, stream>>>(xb, wqkv, bQ, bK, bV, Qb, Kb, Vb);
    attn<<<dim3(NCHUNK * 24), 256, 0, stream>>>(Qb, Kb, Vb, Po, Pl);
    gemm_proj<<<512, 256, 0, stream>>>(Po, Pl, wo, bO, out);
}

// Round 5
// 161.948 us; speedup vs baseline: 1.1256x; 1.1256x over previous
//
#include <hip/hip_runtime.h>
#include <hip/hip_bf16.h>

#define BATCH 2
#define SLEN 2048
#define NH 12
#define DM 768
#define DH 64
#define ROWS (BATCH*SLEN)   // 4096
#define NQKV (3*DM)         // 2304
#define NCHUNK 40           // split-K chunks per bh (q-tile=128, chunk = up to 8 k-tiles)

typedef __attribute__((ext_vector_type(8))) short bf16x8;
typedef __attribute__((ext_vector_type(4))) float f32x4;
typedef __attribute__((ext_vector_type(16))) float f32x16;
typedef unsigned short u16;
typedef unsigned int u32;
typedef __attribute__((ext_vector_type(4))) unsigned short u16x4;
typedef __attribute__((ext_vector_type(8))) unsigned short u16x8;

__device__ __forceinline__ u16 f2b(float f) {
    unsigned int u = __builtin_bit_cast(unsigned int, f);
    unsigned int r = (u + 0x7FFFu + ((u >> 16) & 1u)) >> 16;
    return (u16)r;
}
__device__ __forceinline__ float b2f(u16 v) {
    unsigned int u = ((unsigned int)v) << 16;
    return __builtin_bit_cast(float, u);
}

// async global->LDS, 16B per lane. LDS dest = wave-uniform base + lane*16.
__device__ __forceinline__ void gload16(const u16* g, u16* l) {
    __builtin_amdgcn_global_load_lds(
        (const __attribute__((address_space(1))) unsigned int*)g,
        (__attribute__((address_space(3))) unsigned int*)l,
        16, 0, 0);
}

// ---------------- merged pack kernel (x -> bf16, W_QKV -> Bt layout, W_O -> Bt layout) ----
// grid 2112 = 1536 (x) + 432 (wqkv) + 144 (wo); branch is block-uniform.

__global__ __launch_bounds__(256) void pack_all(const float* __restrict__ x,
                                                const float* __restrict__ WQ, const float* __restrict__ WK,
                                                const float* __restrict__ WV, const float* __restrict__ WO,
                                                u16* __restrict__ xb, u16* __restrict__ wqkv,
                                                u16* __restrict__ wo) {
    __shared__ u16 L[64 * 72];
    int blk = blockIdx.x;
    int t = threadIdx.x;
    if (blk < 1536) {
        int i = blk * 256 + t;
        const float4* xv = (const float4*)x;
        float4 a = xv[i * 2], b = xv[i * 2 + 1];
        u16x8 o;
        o[0] = f2b(a.x); o[1] = f2b(a.y); o[2] = f2b(a.z); o[3] = f2b(a.w);
        o[4] = f2b(b.x); o[5] = f2b(b.y); o[6] = f2b(b.z); o[7] = f2b(b.w);
        *(u16x8*)(xb + (size_t)i * 8) = o;
    } else if (blk < 1968) {
        int idx = blk - 1536;
        int mt = idx % 12, h = (idx / 12) % 12, sel = idx / 144;
        const float* W = sel == 0 ? WQ : (sel == 1 ? WK : WV);
        const float* src = W + ((size_t)h * DM + mt * 64) * DH;
        for (int j = 0; j < 4; j++) {
            int i = t + 256 * j;
            int r = i >> 4, cf = i & 15;
            float4 v = ((const float4*)src)[i];
            u16x4 o; o[0] = f2b(v.x); o[1] = f2b(v.y); o[2] = f2b(v.z); o[3] = f2b(v.w);
            *(u16x4*)&L[r * 72 + cf * 4] = o;
        }
        __syncthreads();
        u16* orow = wqkv + ((size_t)(sel * DM + h * DH)) * DM + mt * 64;
        for (int j = 0; j < 16; j++) {
            int e = t + 256 * j;
            int d = e >> 6, mm = e & 63;
            orow[(size_t)d * DM + mm] = L[mm * 72 + d];
        }
    } else {
        int idx = blk - 1968;
        int bi = idx % 12, bj = idx / 12;
        for (int j = 0; j < 4; j++) {
            int i = t + 256 * j;
            int r = i >> 4, cf = i & 15;
            float4 v = ((const float4*)(WO + (size_t)(bi * 64 + r) * DM + bj * 64))[cf];
            u16x4 o; o[0] = f2b(v.x); o[1] = f2b(v.y); o[2] = f2b(v.z); o[3] = f2b(v.w);
            *(u16x4*)&L[r * 72 + cf * 4] = o;
        }
        __syncthreads();
        for (int j = 0; j < 16; j++) {
            int e = t + 256 * j;
            int c = e >> 6, r = e & 63;
            wo[(size_t)(bj * 64 + c) * DM + bi * 64 + r] = L[r * 72 + c];
        }
    }
}

// ---------------- QKV GEMM (128x96 tile, gload16 staging, XOR-swizzled LDS) ----
// grid 24x32 = 768 blocks -> one full residency wave at 3 blocks/CU, no remainder.
// V epilogue transposes via LDS so V^T [d][s] writes are 256B-contiguous rows.

__global__ __launch_bounds__(256) void gemm_qkv(const u16* __restrict__ A, const u16* __restrict__ Bt,
                                                const float* __restrict__ bQ, const float* __restrict__ bK,
                                                const float* __restrict__ bV,
                                                u16* __restrict__ Qb, u16* __restrict__ Kb, u16* __restrict__ Vb) {
    __shared__ u16 S[128 * 64 + 96 * 64];   // Al | Bl; reused as [96][136] transpose pad
    u16* Al = S;
    u16* Bl = S + 128 * 64;
    int t = threadIdx.x;
    int n0 = blockIdx.x * 96, m0 = blockIdx.y * 128;
    int lane = t & 63, w = t >> 6;
    int ln = lane & 15, qd = lane >> 4;
    int wr = (w & 1) * 64, wc = (w >> 1) * 48;
    int srow = lane >> 3, slot = lane & 7;
    f32x4 acc[4][3] = {};

    for (int kt = 0; kt < DM / 64; kt++) {
        __syncthreads();
        for (int j = 0; j < 4; j++) {
            int r = w * 32 + j * 8 + srow;
            int gc = slot ^ (r & 7);
            gload16(A + (size_t)(m0 + r) * DM + kt * 64 + gc * 8, &Al[(w * 32 + j * 8) * 64]);
        }
        for (int j = 0; j < 3; j++) {
            int r = w * 24 + j * 8 + srow;
            int gc = slot ^ (r & 7);
            gload16(Bt + (size_t)(n0 + r) * DM + kt * 64 + gc * 8, &Bl[(w * 24 + j * 8) * 64]);
        }
        __syncthreads();   // drains vmcnt -> tile visible
        for (int ks = 0; ks < 2; ks++) {
            int sl = ((ks * 4 + qd) ^ (ln & 7)) * 8;
            bf16x8 af[4], bfr[3];
            for (int rt = 0; rt < 4; rt++)
                af[rt] = *(const bf16x8*)&Al[(wr + rt * 16 + ln) * 64 + sl];
            for (int ct = 0; ct < 3; ct++)
                bfr[ct] = *(const bf16x8*)&Bl[(wc + ct * 16 + ln) * 64 + sl];
            for (int rt = 0; rt < 4; rt++)
                for (int ct = 0; ct < 3; ct++)
                    acc[rt][ct] = __builtin_amdgcn_mfma_f32_16x16x32_bf16(af[rt], bfr[ct], acc[rt][ct], 0, 0, 0);
        }
    }
    int sel = n0 / DM;                   // 768/96 = 8 tiles per sel -> uniform per block
    if (sel == 2) {
        // transpose 128(s) x 96(d) tile through LDS -> contiguous V^T row writes
        __syncthreads();                 // all LDS reads done before overwrite
        for (int ct = 0; ct < 3; ct++) {
            int c = wc + ct * 16 + ln;
            float bv = bV[n0 - 2 * DM + c];
            for (int rt = 0; rt < 4; rt++) {
                int s = wr + rt * 16 + qd * 4;
                for (int r = 0; r < 4; r++)
                    S[c * 136 + s + r] = f2b(acc[rt][ct][r] + bv);
            }
        }
        __syncthreads();
        int bb = m0 >> 11, ss0 = m0 & 2047;
        for (int it = 0; it < 6; it++) {
            int e = t + it * 256;
            int c = e >> 4, ck = e & 15;
            int gcol = n0 - 2 * DM + c;
            int hh = gcol >> 6, dd = gcol & 63;
            u16x8 v = *(const u16x8*)&S[c * 136 + ck * 8];
            *(u16x8*)&Vb[(((size_t)bb * NH + hh) * DH + dd) * SLEN + ss0 + ck * 8] = v;
        }
    } else {
        const float* bias = sel == 0 ? bQ : bK;
        u16* Out = sel == 0 ? Qb : Kb;
        const float qs = sel == 0 ? 0.125f * 1.44269504f : 1.0f;
        for (int ct = 0; ct < 3; ct++) {
            int col = n0 - sel * DM + wc + ct * 16 + ln;
            int hh = col >> 6, dd = col & 63;
            float bv = bias[col];
            for (int rt = 0; rt < 4; rt++) {
                int row = m0 + wr + rt * 16 + qd * 4;
                for (int r = 0; r < 4; r++) {
                    int rg = row + r;
                    int bb = rg >> 11, ss = rg & 2047;
                    Out[(((size_t)bb * NH + hh) * SLEN + ss) * DH + dd] = f2b((acc[rt][ct][r] + bv) * qs);
                }
            }
        }
    }
}

// ---------------- split-K flash attention, 32x32 MFMA, LDS-routed P ----
// q-tile = 128 rows, 4 waves x 32q. K/V double-buffered (gload16, XOR-swizzled),
// ONE barrier per k-tile (its vmcnt drain completes the prefetch issued at loop top).
// P scratch per-kb [32q][32k] (8KB) -> LDS 40KB -> 4 blocks/CU.
// P swizzle sw=((l31>>1)&3)<<3: bits 3-4, consistent k^sw on write+read; spreads
// lanes over 8 bank-spans -> <=4-way (was 8-way with (l31&3)).
// grid 960 = 40 chunks x 24 bh; cid = 39 - blk/24 (LPT);
// bh = (blk%24&7)*3 + (blk%24>>3) keeps 3 bh per XCD (K/V L2 residency).

__device__ __forceinline__ void cid2qc(int cid, int& qt, int& c, int& nc) {
    if (cid < 4)       { qt = cid;                   c = 0;               nc = 1; }
    else if (cid < 12) { qt = 4 + ((cid - 4) >> 1);  c = (cid - 4) & 1;   nc = 2; }
    else if (cid < 24) { qt = 8 + (cid - 12) / 3;    c = (cid - 12) % 3;  nc = 3; }
    else               { qt = 12 + ((cid - 24) >> 2); c = (cid - 24) & 3; nc = 4; }
}

__global__ __launch_bounds__(256, 4) void attn(const u16* __restrict__ Qb, const u16* __restrict__ Kb,
                                               const u16* __restrict__ Vtg,
                                               u16* __restrict__ Po, float* __restrict__ Plv) {
    __shared__ u16 Kl[2][64 * 64];
    __shared__ u16 Vt[2][64 * 64];       // [d][k]
    __shared__ u16 Pq[4][32 * 32];       // wave-private per-kb P: [q32][k32], XOR-swizzled
    int blk = blockIdx.x;
    int cid = (NCHUNK - 1) - blk / 24;
    int j24 = blk % 24;
    int bh = (j24 & 7) * 3 + (j24 >> 3);
    int qt, c, nc;
    cid2qc(cid, qt, c, nc);
    int ntiles = 2 * qt + 2;
    int kt0 = c * ntiles / nc, kt1 = (c + 1) * ntiles / nc;
    const u16* Qp = Qb + (size_t)bh * SLEN * DH;
    const u16* Kp = Kb + (size_t)bh * SLEN * DH;
    const u16* Vp = Vtg + (size_t)bh * SLEN * DH;  // [d][s]
    int t = threadIdx.x, lane = t & 63, w = t >> 6;
    int l31 = lane & 31, h = lane >> 5;
    int qg = qt * 128 + w * 32 + l31;
    int srow = lane >> 3, slot = lane & 7;
    int sw = ((l31 >> 1) & 3) << 3;      // P swizzle (u16 units, bits 3-4)

    // Q fragments (B-operand): col q = lane&31, contraction d = ks*16 + 8h + e
    bf16x8 qf[4];
    for (int ks = 0; ks < 4; ks++)
        qf[ks] = *(const bf16x8*)(Qp + (size_t)qg * DH + ks * 16 + h * 8);

    f32x16 o[2] = {};    // o[d][q]: col q=lane&31, d = db*32 + (reg&3)+8*(reg>>2)+4h
    float lsum = 0.f;
    u16* Pw = Pq[w];

    auto stage = [&](int kt, int buf) {
        int k0 = kt * 64;
        for (int j = 0; j < 2; j++) {
            int r = w * 16 + j * 8 + srow;
            int gc = slot ^ (r & 7);
            gload16(Kp + (size_t)(k0 + r) * DH + gc * 8, &Kl[buf][(w * 16 + j * 8) * 64]);
            gload16(Vp + (size_t)r * SLEN + k0 + gc * 8, &Vt[buf][(w * 16 + j * 8) * 64]);
        }
    };

    stage(kt0, 0);
    __syncthreads();   // drains vmcnt -> first tile visible
    int cur = 0;
    for (int kt = kt0; kt < kt1; kt++) {
        int k0 = kt * 64;
        if (kt + 1 < kt1) stage(kt + 1, cur ^ 1);   // prefetch overlaps compute
        const u16* Kc = Kl[cur];
        const u16* Vc = Vt[cur];

        for (int kb = 0; kb < 2; kb++) {
            // QK^T: S[32k x 32q] = K_rows x Q
            f32x16 sf = {};
            for (int ks = 0; ks < 4; ks++) {
                int row = kb * 32 + l31;
                bf16x8 kf = *(const bf16x8*)&Kc[row * 64 + (((ks * 2 + h) ^ (row & 7)) * 8)];
                sf = __builtin_amdgcn_mfma_f32_32x32x16_bf16(kf, qf[ks], sf, 0, 0, 0);
            }
            if (k0 + 63 > qt * 128 + w * 32) {          // diagonal region, wave-uniform
                for (int r = 0; r < 16; r++) {
                    int kg = k0 + kb * 32 + (r & 3) + 8 * (r >> 2) + 4 * h;
                    if (kg > qg) sf[r] = -1e30f;
                }
            }
            // exp2 + truncate-to-bf16 pack via v_perm (consecutive-k pairs)
            u32 pr[8];
            for (int p = 0; p < 8; p++) {
                u32 e0 = __builtin_bit_cast(u32, exp2f(sf[2 * p]));
                u32 e1 = __builtin_bit_cast(u32, exp2f(sf[2 * p + 1]));
                pr[p] = __builtin_amdgcn_perm(e1, e0, 0x07060302u);
            }
            // l partial: sum the SAME truncated bf16 values fed to PV
            for (int p = 0; p < 8; p++) {
                lsum += __builtin_bit_cast(float, pr[p] << 16);
                lsum += __builtin_bit_cast(float, pr[p] & 0xFFFF0000u);
            }
            // store P[q=l31][k-local] pairs (regs (2p,2p+1) -> k = {0,8,16,24}+4h), swizzled
            {
                uint2 s;
                s.x = pr[0]; s.y = pr[1];
                *(uint2*)&Pw[l31 * 32 + ((4 * h) ^ sw)] = s;
                s.x = pr[2]; s.y = pr[3];
                *(uint2*)&Pw[l31 * 32 + ((8 + 4 * h) ^ sw)] = s;
                s.x = pr[4]; s.y = pr[5];
                *(uint2*)&Pw[l31 * 32 + ((16 + 4 * h) ^ sw)] = s;
                s.x = pr[6]; s.y = pr[7];
                *(uint2*)&Pw[l31 * 32 + ((24 + 4 * h) ^ sw)] = s;
            }
            // PV: read B-fragments (col q=l31, k = cc*16 + 8h + e) from swizzled LDS
            for (int cc = 0; cc < 2; cc++) {
                bf16x8 pf = *(const bf16x8*)&Pw[l31 * 32 + ((cc * 16 + 8 * h) ^ sw)];
                int ch4 = kb * 2 + cc;
                for (int db = 0; db < 2; db++) {
                    int row = db * 32 + l31;
                    bf16x8 vf = *(const bf16x8*)&Vc[row * 64 + (((ch4 * 2 + h) ^ (row & 7)) * 8)];
                    o[db] = __builtin_amdgcn_mfma_f32_32x32x16_bf16(vf, pf, o[db], 0, 0, 0);
                }
            }
        }
        __syncthreads();   // drains prefetch vmcnt; buffers safe to swap
        cur ^= 1;
    }

    size_t pid = (size_t)bh * NCHUNK + cid;
    u16* op = Po + pid * (128 * 64);      // [q-local][d]
    for (int db = 0; db < 2; db++)
        for (int rq = 0; rq < 4; rq++) {
            u16x4 ov;
            for (int j = 0; j < 4; j++) ov[j] = f2b(o[db][rq * 4 + j]);
            *(u16x4*)&op[(w * 32 + l31) * 64 + db * 32 + rq * 8 + 4 * h] = ov;
        }
    lsum += __shfl_xor(lsum, 32, 64);     // merge h-halves -> full k-sum for q=l31
    if (h == 0)
        Plv[pid * 128 + w * 32 + l31] = lsum;
}

// ---------------- combine partials -> Z bf16 [4096][768] ----------------

__global__ __launch_bounds__(256) void combine(const u16* __restrict__ Po, const float* __restrict__ Plv,
                                               u16* __restrict__ Zb) {
    int qtile = blockIdx.x, bh = blockIdx.y;   // qtile in [0,16)
    int b = bh / NH, hH = bh % NH;
    int nc = qtile < 4 ? 1 : (qtile < 8 ? 2 : (qtile < 12 ? 3 : 4));
    int base = qtile < 4 ? qtile
             : (qtile < 8 ? 4 + (qtile - 4) * 2
             : (qtile < 12 ? 12 + (qtile - 8) * 3
                           : 24 + (qtile - 12) * 4));
    int t = threadIdx.x;
    int q = t >> 1, dseg = (t & 1) * 32;

    float acc[32] = {};
    float lsum = 0.f;
    for (int cc = 0; cc < nc; cc++) {
        size_t pid = (size_t)bh * NCHUNK + base + cc;
        lsum += Plv[pid * 128 + q];
        const u16* op = Po + pid * (128 * 64) + q * 64 + dseg;
        for (int jj = 0; jj < 4; jj++) {
            u16x8 v = *(const u16x8*)(op + jj * 8);
            for (int e = 0; e < 8; e++)
                acc[jj * 8 + e] += b2f(v[e]);
        }
    }
    float inv = 1.0f / lsum;
    u16* Zp = Zb + ((size_t)b * SLEN + qtile * 128 + q) * DM + hH * DH + dseg;
    for (int jj = 0; jj < 4; jj++) {
        u16x8 ov;
        for (int e = 0; e < 8; e++) ov[e] = f2b(acc[jj * 8 + e] * inv);
        *(u16x8*)(Zp + jj * 8) = ov;
    }
}

// ---------------- output projection (64x96 tile, global_load_lds staging) ----------------
// grid (8, 64) = 512 blocks = 2.0 blocks/CU exact.

__global__ __launch_bounds__(256) void gemm_proj(const u16* __restrict__ A, const u16* __restrict__ Bt,
                                                 const float* __restrict__ bO, float* __restrict__ out) {
    __shared__ u16 Al[64 * 64];
    __shared__ u16 Bl[96 * 64];
    int t = threadIdx.x;
    int n0 = blockIdx.x * 96, m0 = blockIdx.y * 64;
    int lane = t & 63, w = t >> 6;
    int ln = lane & 15, qd = lane >> 4;
    int wr = (w & 1) * 32, wc = (w >> 1) * 48;
    int srow = lane >> 3, slot = lane & 7;
    f32x4 acc[2][3] = {};

    for (int kt = 0; kt < DM / 64; kt++) {
        __syncthreads();
        for (int j = 0; j < 2; j++) {
            int r = w * 16 + j * 8 + srow;
            int gc = slot ^ (r & 7);
            gload16(A + (size_t)(m0 + r) * DM + kt * 64 + gc * 8, &Al[(w * 16 + j * 8) * 64]);
        }
        for (int j = 0; j < 3; j++) {
            int r = w * 24 + j * 8 + srow;
            int gc = slot ^ (r & 7);
            gload16(Bt + (size_t)(n0 + r) * DM + kt * 64 + gc * 8, &Bl[(w * 24 + j * 8) * 64]);
        }
        __syncthreads();
        for (int ks = 0; ks < 2; ks++) {
            int sl = ((ks * 4 + qd) ^ (ln & 7)) * 8;
            bf16x8 af[2], bfr[3];
            for (int rt = 0; rt < 2; rt++)
                af[rt] = *(const bf16x8*)&Al[(wr + rt * 16 + ln) * 64 + sl];
            for (int ct = 0; ct < 3; ct++)
                bfr[ct] = *(const bf16x8*)&Bl[(wc + ct * 16 + ln) * 64 + sl];
            for (int rt = 0; rt < 2; rt++)
                for (int ct = 0; ct < 3; ct++)
                    acc[rt][ct] = __builtin_amdgcn_mfma_f32_16x16x32_bf16(af[rt], bfr[ct], acc[rt][ct], 0, 0, 0);
        }
    }
    for (int ct = 0; ct < 3; ct++) {
        int col = n0 + wc + ct * 16 + ln;
        float bv = bO[col];
        for (int rt = 0; rt < 2; rt++) {
            int row = m0 + wr + rt * 16 + qd * 4;
            for (int r = 0; r < 4; r++)
                out[(size_t)(row + r) * DM + col] = acc[rt][ct][r] + bv;
        }
    }
}

// ---------------- launch ----------------

extern "C" void kernel_launch(void* const* d_in, const int* in_sizes, int n_in,
                              void* d_out, int out_size, void* d_ws, size_t ws_size,
                              hipStream_t stream) {
    const float* x  = (const float*)d_in[0];
    const float* WQ = (const float*)d_in[1];
    const float* bQ = (const float*)d_in[2];
    const float* WK = (const float*)d_in[3];
    const float* bK = (const float*)d_in[4];
    const float* WV = (const float*)d_in[5];
    const float* bV = (const float*)d_in[6];
    const float* WO = (const float*)d_in[7];
    const float* bO = (const float*)d_in[8];
    float* out = (float*)d_out;

    u16* xb   = (u16*)d_ws;                        // [4096][768]
    u16* wqkv = xb + (size_t)ROWS * DM;            // [2304][768]
    u16* wo   = wqkv + (size_t)NQKV * DM;          // [768][768]
    u16* Qb   = wo + (size_t)DM * DM;
    size_t hsz = (size_t)BATCH * NH * SLEN * DH;
    u16* Kb   = Qb + hsz;
    u16* Vb   = Kb + hsz;                          // V^T [b,h,d,s]
    u16* Zb   = Vb + hsz;                          // [4096][768]
    u16* Po   = Zb + (size_t)ROWS * DM;            // partials o: [24*40][128][64] bf16
    float* Pl = (float*)(Po + (size_t)BATCH * NH * NCHUNK * 128 * 64);

    pack_all<<<2112, 256, 0, stream>>>(x, WQ, WK, WV, WO, xb, wqkv, wo);
    gemm_qkv<<<dim3(NQKV / 96, ROWS / 128), 256, 0, stream>>>(xb, wqkv, bQ, bK, bV, Qb, Kb, Vb);
    attn<<<dim3(NCHUNK * 24), 256, 0, stream>>>(Qb, Kb, Vb, Po, Pl);
    combine<<<dim3(SLEN / 128, BATCH * NH), 256, 0, stream>>>(Po, Pl, Zb);
    gemm_proj<<<dim3(DM / 96, ROWS / 64), 256, 0, stream>>>(Zb, wo, bO, out);
}

// Round 6
// 160.012 us; speedup vs baseline: 1.1392x; 1.0121x over previous
//
#include <hip/hip_runtime.h>
#include <hip/hip_bf16.h>

#define BATCH 2
#define SLEN 2048
#define NH 12
#define DM 768
#define DH 64
#define ROWS (BATCH*SLEN)   // 4096
#define NQKV (3*DM)         // 2304
#define NCHUNK 40           // split-K chunks per bh (q-tile=128, chunk = up to 8 k-tiles)

typedef __attribute__((ext_vector_type(8))) short bf16x8;
typedef __attribute__((ext_vector_type(4))) float f32x4;
typedef __attribute__((ext_vector_type(16))) float f32x16;
typedef unsigned short u16;
typedef unsigned int u32;
typedef __attribute__((ext_vector_type(4))) unsigned short u16x4;
typedef __attribute__((ext_vector_type(8))) unsigned short u16x8;

__device__ __forceinline__ u16 f2b(float f) {
    unsigned int u = __builtin_bit_cast(unsigned int, f);
    unsigned int r = (u + 0x7FFFu + ((u >> 16) & 1u)) >> 16;
    return (u16)r;
}
__device__ __forceinline__ float b2f(u16 v) {
    unsigned int u = ((unsigned int)v) << 16;
    return __builtin_bit_cast(float, u);
}

// async global->LDS, 16B per lane. LDS dest = wave-uniform base + lane*16.
__device__ __forceinline__ void gload16(const u16* g, u16* l) {
    __builtin_amdgcn_global_load_lds(
        (const __attribute__((address_space(1))) unsigned int*)g,
        (__attribute__((address_space(3))) unsigned int*)l,
        16, 0, 0);
}

// ---------------- merged pack kernel (x -> bf16, W_QKV -> Bt layout, W_O -> Bt layout) ----
// grid 2112 = 1536 (x) + 432 (wqkv) + 144 (wo); branch is block-uniform.

__global__ __launch_bounds__(256) void pack_all(const float* __restrict__ x,
                                                const float* __restrict__ WQ, const float* __restrict__ WK,
                                                const float* __restrict__ WV, const float* __restrict__ WO,
                                                u16* __restrict__ xb, u16* __restrict__ wqkv,
                                                u16* __restrict__ wo) {
    __shared__ u16 L[64 * 72];
    int blk = blockIdx.x;
    int t = threadIdx.x;
    if (blk < 1536) {
        int i = blk * 256 + t;
        const float4* xv = (const float4*)x;
        float4 a = xv[i * 2], b = xv[i * 2 + 1];
        u16x8 o;
        o[0] = f2b(a.x); o[1] = f2b(a.y); o[2] = f2b(a.z); o[3] = f2b(a.w);
        o[4] = f2b(b.x); o[5] = f2b(b.y); o[6] = f2b(b.z); o[7] = f2b(b.w);
        *(u16x8*)(xb + (size_t)i * 8) = o;
    } else if (blk < 1968) {
        int idx = blk - 1536;
        int mt = idx % 12, h = (idx / 12) % 12, sel = idx / 144;
        const float* W = sel == 0 ? WQ : (sel == 1 ? WK : WV);
        const float* src = W + ((size_t)h * DM + mt * 64) * DH;
        for (int j = 0; j < 4; j++) {
            int i = t + 256 * j;
            int r = i >> 4, cf = i & 15;
            float4 v = ((const float4*)src)[i];
            u16x4 o; o[0] = f2b(v.x); o[1] = f2b(v.y); o[2] = f2b(v.z); o[3] = f2b(v.w);
            *(u16x4*)&L[r * 72 + cf * 4] = o;
        }
        __syncthreads();
        u16* orow = wqkv + ((size_t)(sel * DM + h * DH)) * DM + mt * 64;
        for (int j = 0; j < 16; j++) {
            int e = t + 256 * j;
            int d = e >> 6, mm = e & 63;
            orow[(size_t)d * DM + mm] = L[mm * 72 + d];
        }
    } else {
        int idx = blk - 1968;
        int bi = idx % 12, bj = idx / 12;
        for (int j = 0; j < 4; j++) {
            int i = t + 256 * j;
            int r = i >> 4, cf = i & 15;
            float4 v = ((const float4*)(WO + (size_t)(bi * 64 + r) * DM + bj * 64))[cf];
            u16x4 o; o[0] = f2b(v.x); o[1] = f2b(v.y); o[2] = f2b(v.z); o[3] = f2b(v.w);
            *(u16x4*)&L[r * 72 + cf * 4] = o;
        }
        __syncthreads();
        for (int j = 0; j < 16; j++) {
            int e = t + 256 * j;
            int c = e >> 6, r = e & 63;
            wo[(size_t)(bj * 64 + c) * DM + bi * 64 + r] = L[r * 72 + c];
        }
    }
}

// ---------------- QKV GEMM (128x96 tile, gload16 staging, XOR-swizzled LDS) ----
// grid 24x32 = 768 blocks -> one full residency wave at 3 blocks/CU, no remainder.
// ALL epilogues now route through LDS for coalesced global writes:
//  V: transpose to [d][s], 256B-contiguous V^T rows (proven in R3).
//  Q/K: [s][d] restage -> u16x8 stores in 128B runs (was 48 scalar u16/thread, 32B runs).

__global__ __launch_bounds__(256) void gemm_qkv(const u16* __restrict__ A, const u16* __restrict__ Bt,
                                                const float* __restrict__ bQ, const float* __restrict__ bK,
                                                const float* __restrict__ bV,
                                                u16* __restrict__ Qb, u16* __restrict__ Kb, u16* __restrict__ Vb) {
    __shared__ u16 S[128 * 64 + 96 * 64];   // Al | Bl; reused as epilogue staging
    u16* Al = S;
    u16* Bl = S + 128 * 64;
    int t = threadIdx.x;
    int n0 = blockIdx.x * 96, m0 = blockIdx.y * 128;
    int lane = t & 63, w = t >> 6;
    int ln = lane & 15, qd = lane >> 4;
    int wr = (w & 1) * 64, wc = (w >> 1) * 48;
    int srow = lane >> 3, slot = lane & 7;
    f32x4 acc[4][3] = {};

    for (int kt = 0; kt < DM / 64; kt++) {
        __syncthreads();
        for (int j = 0; j < 4; j++) {
            int r = w * 32 + j * 8 + srow;
            int gc = slot ^ (r & 7);
            gload16(A + (size_t)(m0 + r) * DM + kt * 64 + gc * 8, &Al[(w * 32 + j * 8) * 64]);
        }
        for (int j = 0; j < 3; j++) {
            int r = w * 24 + j * 8 + srow;
            int gc = slot ^ (r & 7);
            gload16(Bt + (size_t)(n0 + r) * DM + kt * 64 + gc * 8, &Bl[(w * 24 + j * 8) * 64]);
        }
        __syncthreads();   // drains vmcnt -> tile visible
        for (int ks = 0; ks < 2; ks++) {
            int sl = ((ks * 4 + qd) ^ (ln & 7)) * 8;
            bf16x8 af[4], bfr[3];
            for (int rt = 0; rt < 4; rt++)
                af[rt] = *(const bf16x8*)&Al[(wr + rt * 16 + ln) * 64 + sl];
            for (int ct = 0; ct < 3; ct++)
                bfr[ct] = *(const bf16x8*)&Bl[(wc + ct * 16 + ln) * 64 + sl];
            for (int rt = 0; rt < 4; rt++)
                for (int ct = 0; ct < 3; ct++)
                    acc[rt][ct] = __builtin_amdgcn_mfma_f32_16x16x32_bf16(af[rt], bfr[ct], acc[rt][ct], 0, 0, 0);
        }
    }
    int sel = n0 / DM;                   // 768/96 = 8 tiles per sel -> uniform per block
    __syncthreads();                     // all fragment LDS reads done before S reuse
    if (sel == 2) {
        // transpose 128(s) x 96(d) tile through LDS -> contiguous V^T row writes
        for (int ct = 0; ct < 3; ct++) {
            int c = wc + ct * 16 + ln;
            float bv = bV[n0 - 2 * DM + c];
            for (int rt = 0; rt < 4; rt++) {
                int s = wr + rt * 16 + qd * 4;
                for (int r = 0; r < 4; r++)
                    S[c * 136 + s + r] = f2b(acc[rt][ct][r] + bv);
            }
        }
        __syncthreads();
        int bb = m0 >> 11, ss0 = m0 & 2047;
        for (int it = 0; it < 6; it++) {
            int e = t + it * 256;
            int c = e >> 4, ck = e & 15;
            int gcol = n0 - 2 * DM + c;
            int hh = gcol >> 6, dd = gcol & 63;
            u16x8 v = *(const u16x8*)&S[c * 136 + ck * 8];
            *(u16x8*)&Vb[(((size_t)bb * NH + hh) * DH + dd) * SLEN + ss0 + ck * 8] = v;
        }
    } else {
        const float* bias = sel == 0 ? bQ : bK;
        u16* Out = sel == 0 ? Qb : Kb;
        const float qs = sel == 0 ? 0.125f * 1.44269504f : 1.0f;
        // restage [s][d] into S [128][104] (pad vs bank cycling), then coalesced u16x8
        for (int ct = 0; ct < 3; ct++) {
            int c = wc + ct * 16 + ln;
            float bv = bias[n0 - sel * DM + c];
            for (int rt = 0; rt < 4; rt++) {
                int s = wr + rt * 16 + qd * 4;
                for (int r = 0; r < 4; r++)
                    S[(s + r) * 104 + c] = f2b((acc[rt][ct][r] + bv) * qs);
            }
        }
        __syncthreads();
        int bb = m0 >> 11, ss0 = m0 & 2047;
        for (int it = 0; it < 6; it++) {
            int e = t + it * 256;            // [0, 1536): 128 s-rows x 12 chunks
            int s = e / 12, c8 = (e - s * 12) * 8;
            int gcol = n0 - sel * DM + c8;
            int hh = gcol >> 6, dd = gcol & 63;
            u16x8 v = *(const u16x8*)&S[s * 104 + c8];
            *(u16x8*)&Out[(((size_t)bb * NH + hh) * SLEN + ss0 + s) * DH + dd] = v;
        }
    }
}

// ---------------- split-K flash attention, 32x32 MFMA, LDS-routed P ----
// q-tile = 128 rows, 4 waves x 32q. K/V double-buffered (gload16, XOR-swizzled),
// ONE barrier per k-tile. P scratch per-kb [32q][32k] (8KB) -> LDS 40KB -> 4 blocks/CU.
// nc==1 chunks (qtile<4): full row-sum available in-kernel -> write normalized Zb
// directly, skipping the Po/combine round trip for those rows.
// grid 960 = 40 chunks x 24 bh; cid = 39 - blk/24 (LPT);
// bh = (blk%24&7)*3 + (blk%24>>3) keeps 3 bh per XCD (K/V L2 residency).

__device__ __forceinline__ void cid2qc(int cid, int& qt, int& c, int& nc) {
    if (cid < 4)       { qt = cid;                   c = 0;               nc = 1; }
    else if (cid < 12) { qt = 4 + ((cid - 4) >> 1);  c = (cid - 4) & 1;   nc = 2; }
    else if (cid < 24) { qt = 8 + (cid - 12) / 3;    c = (cid - 12) % 3;  nc = 3; }
    else               { qt = 12 + ((cid - 24) >> 2); c = (cid - 24) & 3; nc = 4; }
}

__global__ __launch_bounds__(256, 4) void attn(const u16* __restrict__ Qb, const u16* __restrict__ Kb,
                                               const u16* __restrict__ Vtg,
                                               u16* __restrict__ Po, float* __restrict__ Plv,
                                               u16* __restrict__ Zb) {
    __shared__ u16 Kl[2][64 * 64];
    __shared__ u16 Vt[2][64 * 64];       // [d][k]
    __shared__ u16 Pq[4][32 * 32];       // wave-private per-kb P: [q32][k32], XOR-swizzled
    int blk = blockIdx.x;
    int cid = (NCHUNK - 1) - blk / 24;
    int j24 = blk % 24;
    int bh = (j24 & 7) * 3 + (j24 >> 3);
    int qt, c, nc;
    cid2qc(cid, qt, c, nc);
    int ntiles = 2 * qt + 2;
    int kt0 = c * ntiles / nc, kt1 = (c + 1) * ntiles / nc;
    const u16* Qp = Qb + (size_t)bh * SLEN * DH;
    const u16* Kp = Kb + (size_t)bh * SLEN * DH;
    const u16* Vp = Vtg + (size_t)bh * SLEN * DH;  // [d][s]
    int t = threadIdx.x, lane = t & 63, w = t >> 6;
    int l31 = lane & 31, h = lane >> 5;
    int qg = qt * 128 + w * 32 + l31;
    int srow = lane >> 3, slot = lane & 7;
    int sw = ((l31 >> 1) & 3) << 3;      // P swizzle (u16 units, bits 3-4)

    // Q fragments (B-operand): col q = lane&31, contraction d = ks*16 + 8h + e
    bf16x8 qf[4];
    for (int ks = 0; ks < 4; ks++)
        qf[ks] = *(const bf16x8*)(Qp + (size_t)qg * DH + ks * 16 + h * 8);

    f32x16 o[2] = {};    // o[d][q]: col q=lane&31, d = db*32 + (reg&3)+8*(reg>>2)+4h
    float lsum = 0.f;
    u16* Pw = Pq[w];

    auto stage = [&](int kt, int buf) {
        int k0 = kt * 64;
        for (int j = 0; j < 2; j++) {
            int r = w * 16 + j * 8 + srow;
            int gc = slot ^ (r & 7);
            gload16(Kp + (size_t)(k0 + r) * DH + gc * 8, &Kl[buf][(w * 16 + j * 8) * 64]);
            gload16(Vp + (size_t)r * SLEN + k0 + gc * 8, &Vt[buf][(w * 16 + j * 8) * 64]);
        }
    };

    stage(kt0, 0);
    __syncthreads();   // drains vmcnt -> first tile visible
    int cur = 0;
    for (int kt = kt0; kt < kt1; kt++) {
        int k0 = kt * 64;
        if (kt + 1 < kt1) stage(kt + 1, cur ^ 1);   // prefetch overlaps compute
        const u16* Kc = Kl[cur];
        const u16* Vc = Vt[cur];

        for (int kb = 0; kb < 2; kb++) {
            // QK^T: S[32k x 32q] = K_rows x Q
            f32x16 sf = {};
            for (int ks = 0; ks < 4; ks++) {
                int row = kb * 32 + l31;
                bf16x8 kf = *(const bf16x8*)&Kc[row * 64 + (((ks * 2 + h) ^ (row & 7)) * 8)];
                sf = __builtin_amdgcn_mfma_f32_32x32x16_bf16(kf, qf[ks], sf, 0, 0, 0);
            }
            if (k0 + 63 > qt * 128 + w * 32) {          // diagonal region, wave-uniform
                for (int r = 0; r < 16; r++) {
                    int kg = k0 + kb * 32 + (r & 3) + 8 * (r >> 2) + 4 * h;
                    if (kg > qg) sf[r] = -1e30f;
                }
            }
            // exp2 + truncate-to-bf16 pack via v_perm (consecutive-k pairs)
            u32 pr[8];
            for (int p = 0; p < 8; p++) {
                u32 e0 = __builtin_bit_cast(u32, exp2f(sf[2 * p]));
                u32 e1 = __builtin_bit_cast(u32, exp2f(sf[2 * p + 1]));
                pr[p] = __builtin_amdgcn_perm(e1, e0, 0x07060302u);
            }
            // l partial: sum the SAME truncated bf16 values fed to PV
            for (int p = 0; p < 8; p++) {
                lsum += __builtin_bit_cast(float, pr[p] << 16);
                lsum += __builtin_bit_cast(float, pr[p] & 0xFFFF0000u);
            }
            // store P[q=l31][k-local] pairs (regs (2p,2p+1) -> k = {0,8,16,24}+4h), swizzled
            {
                uint2 s;
                s.x = pr[0]; s.y = pr[1];
                *(uint2*)&Pw[l31 * 32 + ((4 * h) ^ sw)] = s;
                s.x = pr[2]; s.y = pr[3];
                *(uint2*)&Pw[l31 * 32 + ((8 + 4 * h) ^ sw)] = s;
                s.x = pr[4]; s.y = pr[5];
                *(uint2*)&Pw[l31 * 32 + ((16 + 4 * h) ^ sw)] = s;
                s.x = pr[6]; s.y = pr[7];
                *(uint2*)&Pw[l31 * 32 + ((24 + 4 * h) ^ sw)] = s;
            }
            // PV: read B-fragments (col q=l31, k = cc*16 + 8h + e) from swizzled LDS
            for (int cc = 0; cc < 2; cc++) {
                bf16x8 pf = *(const bf16x8*)&Pw[l31 * 32 + ((cc * 16 + 8 * h) ^ sw)];
                int ch4 = kb * 2 + cc;
                for (int db = 0; db < 2; db++) {
                    int row = db * 32 + l31;
                    bf16x8 vf = *(const bf16x8*)&Vc[row * 64 + (((ch4 * 2 + h) ^ (row & 7)) * 8)];
                    o[db] = __builtin_amdgcn_mfma_f32_32x32x16_bf16(vf, pf, o[db], 0, 0, 0);
                }
            }
        }
        __syncthreads();   // drains prefetch vmcnt; buffers safe to swap
        cur ^= 1;
    }

    lsum += __shfl_xor(lsum, 32, 64);     // merge h-halves -> full k-sum for q=l31
    if (nc == 1) {
        // full causal range in this chunk: normalize and write Z directly
        float inv = 1.0f / lsum;
        int b = bh / NH, hH = bh % NH;
        u16* Zp = Zb + ((size_t)b * SLEN + qg) * DM + hH * DH;
        for (int db = 0; db < 2; db++)
            for (int rq = 0; rq < 4; rq++) {
                u16x4 ov;
                for (int j = 0; j < 4; j++) ov[j] = f2b(o[db][rq * 4 + j] * inv);
                *(u16x4*)&Zp[db * 32 + rq * 8 + 4 * h] = ov;
            }
    } else {
        size_t pid = (size_t)bh * NCHUNK + cid;
        u16* op = Po + pid * (128 * 64);      // [q-local][d]
        for (int db = 0; db < 2; db++)
            for (int rq = 0; rq < 4; rq++) {
                u16x4 ov;
                for (int j = 0; j < 4; j++) ov[j] = f2b(o[db][rq * 4 + j]);
                *(u16x4*)&op[(w * 32 + l31) * 64 + db * 32 + rq * 8 + 4 * h] = ov;
            }
        if (h == 0)
            Plv[pid * 128 + w * 32 + l31] = lsum;
    }
}

// ---------------- combine partials -> Z bf16 (qtiles 4..15 only) ----------------

__global__ __launch_bounds__(256) void combine(const u16* __restrict__ Po, const float* __restrict__ Plv,
                                               u16* __restrict__ Zb) {
    int qtile = blockIdx.x + 4, bh = blockIdx.y;   // qtile in [4,16)
    int b = bh / NH, hH = bh % NH;
    int nc = qtile < 8 ? 2 : (qtile < 12 ? 3 : 4);
    int base = qtile < 8 ? 4 + (qtile - 4) * 2
             : (qtile < 12 ? 12 + (qtile - 8) * 3
                           : 24 + (qtile - 12) * 4);
    int t = threadIdx.x;
    int q = t >> 1, dseg = (t & 1) * 32;

    float acc[32] = {};
    float lsum = 0.f;
    for (int cc = 0; cc < nc; cc++) {
        size_t pid = (size_t)bh * NCHUNK + base + cc;
        lsum += Plv[pid * 128 + q];
        const u16* op = Po + pid * (128 * 64) + q * 64 + dseg;
        for (int jj = 0; jj < 4; jj++) {
            u16x8 v = *(const u16x8*)(op + jj * 8);
            for (int e = 0; e < 8; e++)
                acc[jj * 8 + e] += b2f(v[e]);
        }
    }
    float inv = 1.0f / lsum;
    u16* Zp = Zb + ((size_t)b * SLEN + qtile * 128 + q) * DM + hH * DH + dseg;
    for (int jj = 0; jj < 4; jj++) {
        u16x8 ov;
        for (int e = 0; e < 8; e++) ov[e] = f2b(acc[jj * 8 + e] * inv);
        *(u16x8*)(Zp + jj * 8) = ov;
    }
}

// ---------------- output projection (64x96 tile, global_load_lds staging) ----------------
// grid (8, 64) = 512 blocks = 2.0 blocks/CU exact.

__global__ __launch_bounds__(256) void gemm_proj(const u16* __restrict__ A, const u16* __restrict__ Bt,
                                                 const float* __restrict__ bO, float* __restrict__ out) {
    __shared__ u16 Al[64 * 64];
    __shared__ u16 Bl[96 * 64];
    int t = threadIdx.x;
    int n0 = blockIdx.x * 96, m0 = blockIdx.y * 64;
    int lane = t & 63, w = t >> 6;
    int ln = lane & 15, qd = lane >> 4;
    int wr = (w & 1) * 32, wc = (w >> 1) * 48;
    int srow = lane >> 3, slot = lane & 7;
    f32x4 acc[2][3] = {};

    for (int kt = 0; kt < DM / 64; kt++) {
        __syncthreads();
        for (int j = 0; j < 2; j++) {
            int r = w * 16 + j * 8 + srow;
            int gc = slot ^ (r & 7);
            gload16(A + (size_t)(m0 + r) * DM + kt * 64 + gc * 8, &Al[(w * 16 + j * 8) * 64]);
        }
        for (int j = 0; j < 3; j++) {
            int r = w * 24 + j * 8 + srow;
            int gc = slot ^ (r & 7);
            gload16(Bt + (size_t)(n0 + r) * DM + kt * 64 + gc * 8, &Bl[(w * 24 + j * 8) * 64]);
        }
        __syncthreads();
        for (int ks = 0; ks < 2; ks++) {
            int sl = ((ks * 4 + qd) ^ (ln & 7)) * 8;
            bf16x8 af[2], bfr[3];
            for (int rt = 0; rt < 2; rt++)
                af[rt] = *(const bf16x8*)&Al[(wr + rt * 16 + ln) * 64 + sl];
            for (int ct = 0; ct < 3; ct++)
                bfr[ct] = *(const bf16x8*)&Bl[(wc + ct * 16 + ln) * 64 + sl];
            for (int rt = 0; rt < 2; rt++)
                for (int ct = 0; ct < 3; ct++)
                    acc[rt][ct] = __builtin_amdgcn_mfma_f32_16x16x32_bf16(af[rt], bfr[ct], acc[rt][ct], 0, 0, 0);
        }
    }
    for (int ct = 0; ct < 3; ct++) {
        int col = n0 + wc + ct * 16 + ln;
        float bv = bO[col];
        for (int rt = 0; rt < 2; rt++) {
            int row = m0 + wr + rt * 16 + qd * 4;
            for (int r = 0; r < 4; r++)
                out[(size_t)(row + r) * DM + col] = acc[rt][ct][r] + bv;
        }
    }
}

// ---------------- launch ----------------

extern "C" void kernel_launch(void* const* d_in, const int* in_sizes, int n_in,
                              void* d_out, int out_size, void* d_ws, size_t ws_size,
                              hipStream_t stream) {
    const float* x  = (const float*)d_in[0];
    const float* WQ = (const float*)d_in[1];
    const float* bQ = (const float*)d_in[2];
    const float* WK = (const float*)d_in[3];
    const float* bK = (const float*)d_in[4];
    const float* WV = (const float*)d_in[5];
    const float* bV = (const float*)d_in[6];
    const float* WO = (const float*)d_in[7];
    const float* bO = (const float*)d_in[8];
    float* out = (float*)d_out;

    u16* xb   = (u16*)d_ws;                        // [4096][768]
    u16* wqkv = xb + (size_t)ROWS * DM;            // [2304][768]
    u16* wo   = wqkv + (size_t)NQKV * DM;          // [768][768]
    u16* Qb   = wo + (size_t)DM * DM;
    size_t hsz = (size_t)BATCH * NH * SLEN * DH;
    u16* Kb   = Qb + hsz;
    u16* Vb   = Kb + hsz;                          // V^T [b,h,d,s]
    u16* Zb   = Vb + hsz;                          // [4096][768]
    u16* Po   = Zb + (size_t)ROWS * DM;            // partials o: [24*40][128][64] bf16
    float* Pl = (float*)(Po + (size_t)BATCH * NH * NCHUNK * 128 * 64);

    pack_all<<<2112, 256, 0, stream>>>(x, WQ, WK, WV, WO, xb, wqkv, wo);
    gemm_qkv<<<dim3(NQKV / 96, ROWS / 128), 256, 0, stream>>>(xb, wqkv, bQ, bK, bV, Qb, Kb, Vb);
    attn<<<dim3(NCHUNK * 24), 256, 0, stream>>>(Qb, Kb, Vb, Po, Pl, Zb);
    combine<<<dim3(12, BATCH * NH), 256, 0, stream>>>(Po, Pl, Zb);
    gemm_proj<<<dim3(DM / 96, ROWS / 64), 256, 0, stream>>>(Zb, wo, bO, out);
}